// Round 10
// baseline (686.318 us; speedup 1.0000x reference)
//
#include <hip/hip_runtime.h>
#include <hip/hip_bf16.h>
#include <math.h>

// Problem constants
#define BB 16
#define SS 512
#define DD 256
#define HH 8
#define DKk 32
#define LL 2
#define DFF 1024
#define MAXREL 16
#define NLc 25
#define MM (BB*SS)   // 8192

typedef __attribute__((ext_vector_type(4))) _Float16 half4;
typedef __attribute__((ext_vector_type(8))) _Float16 half8;
typedef __attribute__((ext_vector_type(4))) float floatx4;

// ---------------------------------------------------------------------------
// gather concat: xcat[m][k] = k<256 ? char_emb[cid[m]][k] : bigram_emb[bid[m]][k-256]
__global__ __launch_bounds__(256) void gather_kernel(const int* __restrict__ cid,
                                                     const int* __restrict__ bid,
                                                     const float* __restrict__ ce,
                                                     const float* __restrict__ be,
                                                     float* __restrict__ xcat) {
    int idx = blockIdx.x * 256 + threadIdx.x;      // m*512 + k
    int m = idx >> 9, k = idx & 511;
    float v;
    if (k < 256) v = ce[(size_t)cid[m] * 256 + k];
    else         v = be[(size_t)bid[m] * 256 + (k - 256)];
    xcat[idx] = v;
}

// ---------------------------------------------------------------------------
// add sinusoidal PE
__global__ __launch_bounds__(256) void add_pe_kernel(float* __restrict__ x) {
    int idx = blockIdx.x * 256 + threadIdx.x;      // m*256 + n
    int n = idx & 255, m = idx >> 8;
    int s = m & (SS - 1);
    float ang = (float)s * expf(-(float)(n & ~1) * (9.210340371976184f / 256.f));
    x[idx] += (n & 1) ? cosf(ang) : sinf(ang);
}

// ---------------------------------------------------------------------------
// MFMA f16 GEMM v2: out = (relu?)(A@W + bias), fp32 in/out, f16 staging,
// fp32 accumulate. 64x64 tile, BK=64, 4 waves (2x2), wave = 32x32 via
// 2x2 frags of v_mfma_f32_16x16x32_f16 (half8 frags, b128 LDS reads).
// A frag: row=lane&15, k=(lane>>4)*8+j. B frag: col=lane&15, same k (Bs is
// [n][k] transposed at staging). C/D: col=lane&15, row=(lane>>4)*4+i.
// Requires: M%64==0, N%64==0, K%64==0.
__global__ __launch_bounds__(256) void mfma_gemm_kernel(const float* __restrict__ A,
                                                        const float* __restrict__ W,
                                                        const float* __restrict__ bias,
                                                        float* __restrict__ out,
                                                        int M, int K, int N, int relu) {
    __shared__ _Float16 As[64][72];   // [m][k], stride 144B (16B-aligned)
    __shared__ _Float16 Bs[64][72];   // [n][k], transposed at staging
    const int tid = threadIdx.x;
    const int l  = tid & 63;
    const int w  = tid >> 6;
    const int wm = w >> 1, wn = w & 1;
    const int lr = l & 15, lg = l >> 4;       // lg 0..3
    const int m0 = blockIdx.y * 64, n0 = blockIdx.x * 64;

    floatx4 acc[2][2] = {};
    const int ar = tid >> 2, ac = (tid & 3) * 16;   // A: row, 16-float col seg
    const int bk = tid >> 2, bn = (tid & 3) * 16;   // B: k-row, 16-float n seg

    for (int k0 = 0; k0 < K; k0 += 64) {
        __syncthreads();   // previous tile's fragment reads done
        {   // A tile: 64x64 fp32 -> f16, row-major
            const float* src = &A[(size_t)(m0 + ar) * K + k0 + ac];
            float4 f0 = *(const float4*)&src[0];
            float4 f1 = *(const float4*)&src[4];
            float4 f2 = *(const float4*)&src[8];
            float4 f3 = *(const float4*)&src[12];
            half8 h0 = { (_Float16)f0.x, (_Float16)f0.y, (_Float16)f0.z, (_Float16)f0.w,
                         (_Float16)f1.x, (_Float16)f1.y, (_Float16)f1.z, (_Float16)f1.w };
            half8 h1 = { (_Float16)f2.x, (_Float16)f2.y, (_Float16)f2.z, (_Float16)f2.w,
                         (_Float16)f3.x, (_Float16)f3.y, (_Float16)f3.z, (_Float16)f3.w };
            *(half8*)&As[ar][ac]     = h0;
            *(half8*)&As[ar][ac + 8] = h1;
        }
        {   // B tile: W[k0+bk][n0+bn..+15] -> Bs[n][k] (transpose)
            const float* src = &W[(size_t)(k0 + bk) * N + n0 + bn];
            float4 f0 = *(const float4*)&src[0];
            float4 f1 = *(const float4*)&src[4];
            float4 f2 = *(const float4*)&src[8];
            float4 f3 = *(const float4*)&src[12];
            Bs[bn +  0][bk] = (_Float16)f0.x;
            Bs[bn +  1][bk] = (_Float16)f0.y;
            Bs[bn +  2][bk] = (_Float16)f0.z;
            Bs[bn +  3][bk] = (_Float16)f0.w;
            Bs[bn +  4][bk] = (_Float16)f1.x;
            Bs[bn +  5][bk] = (_Float16)f1.y;
            Bs[bn +  6][bk] = (_Float16)f1.z;
            Bs[bn +  7][bk] = (_Float16)f1.w;
            Bs[bn +  8][bk] = (_Float16)f2.x;
            Bs[bn +  9][bk] = (_Float16)f2.y;
            Bs[bn + 10][bk] = (_Float16)f2.z;
            Bs[bn + 11][bk] = (_Float16)f2.w;
            Bs[bn + 12][bk] = (_Float16)f3.x;
            Bs[bn + 13][bk] = (_Float16)f3.y;
            Bs[bn + 14][bk] = (_Float16)f3.z;
            Bs[bn + 15][bk] = (_Float16)f3.w;
        }
        __syncthreads();
        #pragma unroll
        for (int ks = 0; ks < 2; ++ks) {
            half8 a0 = *(half8*)&As[wm * 32 +      lr][ks * 32 + lg * 8];
            half8 a1 = *(half8*)&As[wm * 32 + 16 + lr][ks * 32 + lg * 8];
            half8 b0 = *(half8*)&Bs[wn * 32 +      lr][ks * 32 + lg * 8];
            half8 b1 = *(half8*)&Bs[wn * 32 + 16 + lr][ks * 32 + lg * 8];
            acc[0][0] = __builtin_amdgcn_mfma_f32_16x16x32_f16(a0, b0, acc[0][0], 0, 0, 0);
            acc[0][1] = __builtin_amdgcn_mfma_f32_16x16x32_f16(a0, b1, acc[0][1], 0, 0, 0);
            acc[1][0] = __builtin_amdgcn_mfma_f32_16x16x32_f16(a1, b0, acc[1][0], 0, 0, 0);
            acc[1][1] = __builtin_amdgcn_mfma_f32_16x16x32_f16(a1, b1, acc[1][1], 0, 0, 0);
        }
    }
    #pragma unroll
    for (int fm = 0; fm < 2; ++fm)
        #pragma unroll
        for (int fn = 0; fn < 2; ++fn)
            #pragma unroll
            for (int i = 0; i < 4; ++i) {
                int row = m0 + wm * 32 + fm * 16 + lg * 4 + i;
                int col = n0 + wn * 32 + fn * 16 + lr;
                float vv = acc[fm][fn][i] + bias[col];
                if (relu) vv = fmaxf(vv, 0.f);
                out[(size_t)row * N + col] = vv;
            }
}

// ---------------------------------------------------------------------------
// fp32 GEMM fallback for ragged N (classifier N=25)
__global__ __launch_bounds__(256) void gemm_kernel(const float* __restrict__ A,
                                                   const float* __restrict__ W,
                                                   const float* __restrict__ bias,
                                                   float* __restrict__ out,
                                                   int M, int K, int N, int relu) {
    __shared__ float As[16][68];
    __shared__ float Bs[16][68];
    const int tid = threadIdx.x;
    const int tx = tid & 15, ty = tid >> 4;
    const int n0 = blockIdx.x * 64;
    const int m0 = blockIdx.y * 64;
    float acc[4][4] = {};
    for (int kk = 0; kk < K; kk += 16) {
        {
            int k = tid & 15;
            int ib = tid >> 4;
            #pragma unroll
            for (int it = 0; it < 4; ++it) {
                int i = ib + it * 16;
                As[k][i] = A[(size_t)(m0 + i) * K + kk + k];
            }
        }
        {
            int j = tid & 63;
            int kb = tid >> 6;
            int n = n0 + j;
            #pragma unroll
            for (int it = 0; it < 4; ++it) {
                int k = kb + it * 4;
                Bs[k][j] = (n < N) ? W[(size_t)(kk + k) * N + n] : 0.f;
            }
        }
        __syncthreads();
        #pragma unroll
        for (int k = 0; k < 16; ++k) {
            float a[4], b[4];
            #pragma unroll
            for (int r = 0; r < 4; ++r) a[r] = As[k][ty * 4 + r];
            #pragma unroll
            for (int c = 0; c < 4; ++c) b[c] = Bs[k][tx * 4 + c];
            #pragma unroll
            for (int r = 0; r < 4; ++r)
                #pragma unroll
                for (int c = 0; c < 4; ++c)
                    acc[r][c] += a[r] * b[c];
        }
        __syncthreads();
    }
    #pragma unroll
    for (int r = 0; r < 4; ++r) {
        int m = m0 + ty * 4 + r;
        #pragma unroll
        for (int c = 0; c < 4; ++c) {
            int n = n0 + tx * 4 + c;
            if (n < N) {
                float v = acc[r][c] + bias[n];
                if (relu) v = fmaxf(v, 0.f);
                out[(size_t)m * N + n] = v;
            }
        }
    }
}

// ---------------------------------------------------------------------------
// flash-style attention v2: one block per (32-query tile, h, b). Online
// softmax over 8 chunks of 64 keys. K and V staged together (one latency
// exposure, 3 barriers per chunk). QK reads vectorized float4.
__global__ __launch_bounds__(256) void attn_kernel(const float* __restrict__ q,
                                                   const float* __restrict__ k,
                                                   const float* __restrict__ v,
                                                   const float* __restrict__ rel,
                                                   const int* __restrict__ mask,
                                                   float* __restrict__ ctx) {
    __shared__ float kv[128][36];     // rows 0..63 K, 64..127 V
    __shared__ float sc[32][68];
    __shared__ float qrel[32][36];
    __shared__ float relS[33][36];
    __shared__ float scaleS[32];
    __shared__ float lS[32];

    const int tid = threadIdx.x;
    const int it0 = blockIdx.x * 32;
    const int h = blockIdx.y;
    const int b = blockIdx.z;
    const size_t base = ((size_t)b * SS) * DD + (size_t)h * 32;

    // preamble: q tile into kv[0..31], rel table; qrel[i][t] = q_i . rel_t
    for (int e = tid; e < 32 * 8; e += 256) {
        int i = e >> 3, dq = e & 7;
        *(float4*)&kv[i][dq * 4] =
            *(const float4*)&q[base + (size_t)(it0 + i) * DD + dq * 4];
    }
    for (int e = tid; e < 33 * 8; e += 256) {
        int t = e >> 3, dq = e & 7;
        *(float4*)&relS[t][dq * 4] = *(const float4*)&rel[t * 32 + dq * 4];
    }
    __syncthreads();
    for (int e = tid; e < 32 * 33; e += 256) {
        int i = e / 33, t = e % 33;
        float acc = 0.f;
        #pragma unroll
        for (int d = 0; d < 32; ++d) acc += kv[i][d] * relS[t][d];
        qrel[i][t] = acc;
    }

    const int rp = tid >> 4, g = tid & 15;
    const int r0 = 2 * rp, r1 = 2 * rp + 1;
    const int pi = tid >> 3, gg = tid & 7;

    float q0[32], q1[32];
    #pragma unroll
    for (int dq = 0; dq < 8; ++dq) {
        float4 a = *(float4*)&kv[r0][dq * 4];
        q0[dq * 4 + 0] = a.x; q0[dq * 4 + 1] = a.y;
        q0[dq * 4 + 2] = a.z; q0[dq * 4 + 3] = a.w;
        float4 c = *(float4*)&kv[r1][dq * 4];
        q1[dq * 4 + 0] = c.x; q1[dq * 4 + 1] = c.y;
        q1[dq * 4 + 2] = c.z; q1[dq * 4 + 3] = c.w;
    }

    const float scale = 0.17677669529663687f;  // 1/sqrt(32)
    float m0 = -1e30f, m1 = -1e30f, l0 = 0.f, l1 = 0.f;
    float acc4[4] = {0.f, 0.f, 0.f, 0.f};

    for (int jc = 0; jc < 8; ++jc) {
        const int j0 = jc * 64;
        __syncthreads();   // kv free (q-reg reads / prev PV done)
        // stage K chunk (rows 0..63) and V chunk (rows 64..127) together
        #pragma unroll
        for (int it = 0; it < 2; ++it) {
            int e = tid * 2 + it;
            int j = e >> 3, dq = e & 7;
            *(float4*)&kv[j][dq * 4] =
                *(const float4*)&k[base + (size_t)(j0 + j) * DD + dq * 4];
            *(float4*)&kv[64 + j][dq * 4] =
                *(const float4*)&v[base + (size_t)(j0 + j) * DD + dq * 4];
        }
        __syncthreads();
        // scores (4 per row), float4 K reads
        float p0[4], p1[4];
        #pragma unroll
        for (int u = 0; u < 4; ++u) {
            int j = g + 16 * u;
            int jg = j0 + j;
            float a0 = 0.f, a1 = 0.f;
            #pragma unroll
            for (int d4 = 0; d4 < 8; ++d4) {
                float4 kk = *(float4*)&kv[j][d4 * 4];
                a0 += q0[d4 * 4 + 0] * kk.x + q0[d4 * 4 + 1] * kk.y
                    + q0[d4 * 4 + 2] * kk.z + q0[d4 * 4 + 3] * kk.w;
                a1 += q1[d4 * 4 + 0] * kk.x + q1[d4 * 4 + 1] * kk.y
                    + q1[d4 * 4 + 2] * kk.z + q1[d4 * 4 + 3] * kk.w;
            }
            int t0 = jg - (it0 + r0);
            t0 = (t0 < -MAXREL ? -MAXREL : (t0 > MAXREL ? MAXREL : t0)) + MAXREL;
            int t1 = jg - (it0 + r1);
            t1 = (t1 < -MAXREL ? -MAXREL : (t1 > MAXREL ? MAXREL : t1)) + MAXREL;
            float v0 = a0 * scale + qrel[r0][t0];
            float v1 = a1 * scale + qrel[r1][t1];
            if (mask[b * SS + jg] == 0) { v0 = -1e9f; v1 = -1e9f; }
            p0[u] = v0; p1[u] = v1;
        }
        // online softmax update (reduce over 16 j-lanes)
        float cm0 = fmaxf(fmaxf(p0[0], p0[1]), fmaxf(p0[2], p0[3]));
        float cm1 = fmaxf(fmaxf(p1[0], p1[1]), fmaxf(p1[2], p1[3]));
        #pragma unroll
        for (int w = 1; w < 16; w <<= 1) {
            cm0 = fmaxf(cm0, __shfl_xor(cm0, w));
            cm1 = fmaxf(cm1, __shfl_xor(cm1, w));
        }
        float nm0 = fmaxf(m0, cm0), nm1 = fmaxf(m1, cm1);
        float rs0 = __expf(m0 - nm0), rs1 = __expf(m1 - nm1);
        float s0 = 0.f, s1 = 0.f;
        #pragma unroll
        for (int u = 0; u < 4; ++u) {
            p0[u] = __expf(p0[u] - nm0); s0 += p0[u];
            p1[u] = __expf(p1[u] - nm1); s1 += p1[u];
        }
        #pragma unroll
        for (int w = 1; w < 16; w <<= 1) {
            s0 += __shfl_xor(s0, w);
            s1 += __shfl_xor(s1, w);
        }
        l0 = l0 * rs0 + s0; l1 = l1 * rs1 + s1;
        m0 = nm0; m1 = nm1;
        #pragma unroll
        for (int u = 0; u < 4; ++u) {
            sc[r0][g + 16 * u] = p0[u];
            sc[r1][g + 16 * u] = p1[u];
        }
        if (g == 0) { scaleS[r0] = rs0; scaleS[r1] = rs1; }
        __syncthreads();   // p & scale visible to PV threads
        // PV accumulate (V already resident at rows 64..127)
        float rs = scaleS[pi];
        acc4[0] *= rs; acc4[1] *= rs; acc4[2] *= rs; acc4[3] *= rs;
        #pragma unroll
        for (int jq = 0; jq < 16; ++jq) {
            float4 p4 = *(float4*)&sc[pi][jq * 4];
            float4 v0 = *(float4*)&kv[64 + jq * 4 + 0][gg * 4];
            float4 v1 = *(float4*)&kv[64 + jq * 4 + 1][gg * 4];
            float4 v2 = *(float4*)&kv[64 + jq * 4 + 2][gg * 4];
            float4 v3 = *(float4*)&kv[64 + jq * 4 + 3][gg * 4];
            acc4[0] += p4.x * v0.x + p4.y * v1.x + p4.z * v2.x + p4.w * v3.x;
            acc4[1] += p4.x * v0.y + p4.y * v1.y + p4.z * v2.y + p4.w * v3.y;
            acc4[2] += p4.x * v0.z + p4.y * v1.z + p4.z * v2.z + p4.w * v3.z;
            acc4[3] += p4.x * v0.w + p4.y * v1.w + p4.z * v2.w + p4.w * v3.w;
        }
    }
    if (g == 0) { lS[r0] = l0; lS[r1] = l1; }
    __syncthreads();
    float inv = 1.f / lS[pi];
    float4 o;
    o.x = acc4[0] * inv; o.y = acc4[1] * inv;
    o.z = acc4[2] * inv; o.w = acc4[3] * inv;
    *(float4*)&ctx[base + (size_t)(it0 + pi) * DD + gg * 4] = o;
}

// ---------------------------------------------------------------------------
// out[m] = LayerNorm(a[m] + res[m]) * g + beta ; one block per row, D=256
__global__ __launch_bounds__(256) void add_ln_kernel(const float* __restrict__ a,
                                                     const float* __restrict__ res,
                                                     const float* __restrict__ g,
                                                     const float* __restrict__ beta,
                                                     float* __restrict__ out) {
    __shared__ float red[4];
    int m = blockIdx.x;
    int n = threadIdx.x;
    size_t idx = (size_t)m * DD + n;
    float v = a[idx] + res[idx];
    float s = v;
    for (int w = 1; w < 64; w <<= 1) s += __shfl_xor(s, w);
    if ((n & 63) == 0) red[n >> 6] = s;
    __syncthreads();
    float mean = (red[0] + red[1] + red[2] + red[3]) * (1.f / 256.f);
    __syncthreads();
    float d = v - mean;
    float s2 = d * d;
    for (int w = 1; w < 64; w <<= 1) s2 += __shfl_xor(s2, w);
    if ((n & 63) == 0) red[n >> 6] = s2;
    __syncthreads();
    float var = (red[0] + red[1] + red[2] + red[3]) * (1.f / 256.f);
    float r = rsqrtf(var + 1e-5f);
    out[idx] = d * r * g[n] + beta[n];
}

// ---------------------------------------------------------------------------
extern "C" void kernel_launch(void* const* d_in, const int* in_sizes, int n_in,
                              void* d_out, int out_size, void* d_ws, size_t ws_size,
                              hipStream_t stream) {
    const int*   char_ids   = (const int*)d_in[0];
    const int*   bigram_ids = (const int*)d_in[1];
    const int*   mask       = (const int*)d_in[2];
    const float* char_emb   = (const float*)d_in[3];
    const float* bigram_emb = (const float*)d_in[4];
    const float* comb_W     = (const float*)d_in[5];
    const float* comb_b     = (const float*)d_in[6];
    const float* Wq         = (const float*)d_in[7];
    const float* bq         = (const float*)d_in[8];
    const float* Wk         = (const float*)d_in[9];
    const float* bk         = (const float*)d_in[10];
    const float* Wv         = (const float*)d_in[11];
    const float* bv         = (const float*)d_in[12];
    const float* Wo         = (const float*)d_in[13];
    const float* bo         = (const float*)d_in[14];
    const float* rel_emb    = (const float*)d_in[15];
    const float* ln1_g      = (const float*)d_in[16];
    const float* ln1_b      = (const float*)d_in[17];
    const float* W1         = (const float*)d_in[18];
    const float* b1         = (const float*)d_in[19];
    const float* W2         = (const float*)d_in[20];
    const float* b2         = (const float*)d_in[21];
    const float* ln2_g      = (const float*)d_in[22];
    const float* ln2_b      = (const float*)d_in[23];
    const float* cls_W      = (const float*)d_in[24];
    const float* cls_b      = (const float*)d_in[25];
    (void)in_sizes; (void)n_in; (void)out_size; (void)ws_size;

    float* ws = (float*)d_ws;
    const size_t MF = 1024 * 1024;
    float* bufA = ws;                 // 8M floats
    float* x    = ws + 8 * MF;
    float* x2   = ws + 10 * MF;
    float* qb   = ws + 12 * MF;
    float* kb   = ws + 14 * MF;
    float* vb   = ws + 16 * MF;
    float* ctxb = ws + 18 * MF;

    dim3 thr(256);

    gather_kernel<<<MM * 512 / 256, thr, 0, stream>>>(char_ids, bigram_ids,
                                                      char_emb, bigram_emb, bufA);
    mfma_gemm_kernel<<<dim3(DD / 64, MM / 64), thr, 0, stream>>>(bufA, comb_W, comb_b, x,
                                                                 MM, 2 * DD, DD, 0);
    add_pe_kernel<<<MM * DD / 256, thr, 0, stream>>>(x);

    for (int l = 0; l < LL; ++l) {
        const float* wq = Wq + (size_t)l * DD * DD;
        const float* wk = Wk + (size_t)l * DD * DD;
        const float* wv = Wv + (size_t)l * DD * DD;
        const float* wo = Wo + (size_t)l * DD * DD;
        mfma_gemm_kernel<<<dim3(DD / 64, MM / 64), thr, 0, stream>>>(x, wq, bq + l * DD, qb,
                                                                     MM, DD, DD, 0);
        mfma_gemm_kernel<<<dim3(DD / 64, MM / 64), thr, 0, stream>>>(x, wk, bk + l * DD, kb,
                                                                     MM, DD, DD, 0);
        mfma_gemm_kernel<<<dim3(DD / 64, MM / 64), thr, 0, stream>>>(x, wv, bv + l * DD, vb,
                                                                     MM, DD, DD, 0);
        attn_kernel<<<dim3(SS / 32, HH, BB), thr, 0, stream>>>(qb, kb, vb,
                                                               rel_emb + (size_t)l * 33 * 32,
                                                               mask, ctxb);
        mfma_gemm_kernel<<<dim3(DD / 64, MM / 64), thr, 0, stream>>>(ctxb, wo, bo + l * DD, qb,
                                                                     MM, DD, DD, 0);
        add_ln_kernel<<<MM, thr, 0, stream>>>(qb, x, ln1_g + l * DD, ln1_b + l * DD, x2);
        mfma_gemm_kernel<<<dim3(DFF / 64, MM / 64), thr, 0, stream>>>(x2, W1 + (size_t)l * DD * DFF,
                                                                      b1 + l * DFF, bufA,
                                                                      MM, DD, DFF, 1);
        mfma_gemm_kernel<<<dim3(DD / 64, MM / 64), thr, 0, stream>>>(bufA, W2 + (size_t)l * DFF * DD,
                                                                     b2 + l * DD, kb,
                                                                     MM, DFF, DD, 0);
        add_ln_kernel<<<MM, thr, 0, stream>>>(kb, x2, ln2_g + l * DD, ln2_b + l * DD, x);
    }
    gemm_kernel<<<dim3(1, MM / 64), thr, 0, stream>>>(x, cls_W, cls_b, (float*)d_out,
                                                      MM, DD, NLc, 0);
}

// Round 14
// 505.401 us; speedup vs baseline: 1.3580x; 1.3580x over previous
//
#include <hip/hip_runtime.h>
#include <hip/hip_bf16.h>
#include <math.h>

// Problem constants
#define BB 16
#define SS 512
#define DD 256
#define HH 8
#define DKk 32
#define LL 2
#define DFF 1024
#define MAXREL 16
#define NLc 25
#define MM (BB*SS)   // 8192

typedef __attribute__((ext_vector_type(4))) _Float16 half4;
typedef __attribute__((ext_vector_type(8))) _Float16 half8;
typedef __attribute__((ext_vector_type(4))) float floatx4;

__device__ inline half8 cvt8(float4 a, float4 b) {
    half8 h = { (_Float16)a.x, (_Float16)a.y, (_Float16)a.z, (_Float16)a.w,
                (_Float16)b.x, (_Float16)b.y, (_Float16)b.z, (_Float16)b.w };
    return h;
}

// ---------------------------------------------------------------------------
// gather concat: xcat[m][k] = k<256 ? char_emb[cid[m]][k] : bigram_emb[bid[m]][k-256]
__global__ __launch_bounds__(256) void gather_kernel(const int* __restrict__ cid,
                                                     const int* __restrict__ bid,
                                                     const float* __restrict__ ce,
                                                     const float* __restrict__ be,
                                                     float* __restrict__ xcat) {
    int idx = blockIdx.x * 256 + threadIdx.x;      // m*512 + k
    int m = idx >> 9, k = idx & 511;
    float v;
    if (k < 256) v = ce[(size_t)cid[m] * 256 + k];
    else         v = be[(size_t)bid[m] * 256 + (k - 256)];
    xcat[idx] = v;
}

// ---------------------------------------------------------------------------
// add sinusoidal PE
__global__ __launch_bounds__(256) void add_pe_kernel(float* __restrict__ x) {
    int idx = blockIdx.x * 256 + threadIdx.x;      // m*256 + n
    int n = idx & 255, m = idx >> 8;
    int s = m & (SS - 1);
    float ang = (float)s * expf(-(float)(n & ~1) * (9.210340371976184f / 256.f));
    x[idx] += (n & 1) ? cosf(ang) : sinf(ang);
}

// ---------------------------------------------------------------------------
// MFMA f16 GEMM v2 (verified R10): out = (relu?)(A@W + bias), 64x64 tile,
// BK=64, 4 waves (2x2), wave = 32x32 via 2x2 frags of mfma_f32_16x16x32_f16.
__global__ __launch_bounds__(256) void mfma_gemm_kernel(const float* __restrict__ A,
                                                        const float* __restrict__ W,
                                                        const float* __restrict__ bias,
                                                        float* __restrict__ out,
                                                        int M, int K, int N, int relu) {
    __shared__ _Float16 As[64][72];   // [m][k], stride 144B (16B-aligned)
    __shared__ _Float16 Bs[64][72];   // [n][k], transposed at staging
    const int tid = threadIdx.x;
    const int l  = tid & 63;
    const int w  = tid >> 6;
    const int wm = w >> 1, wn = w & 1;
    const int lr = l & 15, lg = l >> 4;       // lg 0..3
    const int m0 = blockIdx.y * 64, n0 = blockIdx.x * 64;

    floatx4 acc[2][2] = {};
    const int ar = tid >> 2, ac = (tid & 3) * 16;   // A: row, 16-float col seg
    const int bk = tid >> 2, bn = (tid & 3) * 16;   // B: k-row, 16-float n seg

    for (int k0 = 0; k0 < K; k0 += 64) {
        __syncthreads();
        {   // A tile: 64x64 fp32 -> f16, row-major
            const float* src = &A[(size_t)(m0 + ar) * K + k0 + ac];
            float4 f0 = *(const float4*)&src[0];
            float4 f1 = *(const float4*)&src[4];
            float4 f2 = *(const float4*)&src[8];
            float4 f3 = *(const float4*)&src[12];
            *(half8*)&As[ar][ac]     = cvt8(f0, f1);
            *(half8*)&As[ar][ac + 8] = cvt8(f2, f3);
        }
        {   // B tile: W[k0+bk][n0+bn..+15] -> Bs[n][k] (transpose)
            const float* src = &W[(size_t)(k0 + bk) * N + n0 + bn];
            float4 f0 = *(const float4*)&src[0];
            float4 f1 = *(const float4*)&src[4];
            float4 f2 = *(const float4*)&src[8];
            float4 f3 = *(const float4*)&src[12];
            Bs[bn +  0][bk] = (_Float16)f0.x;
            Bs[bn +  1][bk] = (_Float16)f0.y;
            Bs[bn +  2][bk] = (_Float16)f0.z;
            Bs[bn +  3][bk] = (_Float16)f0.w;
            Bs[bn +  4][bk] = (_Float16)f1.x;
            Bs[bn +  5][bk] = (_Float16)f1.y;
            Bs[bn +  6][bk] = (_Float16)f1.z;
            Bs[bn +  7][bk] = (_Float16)f1.w;
            Bs[bn +  8][bk] = (_Float16)f2.x;
            Bs[bn +  9][bk] = (_Float16)f2.y;
            Bs[bn + 10][bk] = (_Float16)f2.z;
            Bs[bn + 11][bk] = (_Float16)f2.w;
            Bs[bn + 12][bk] = (_Float16)f3.x;
            Bs[bn + 13][bk] = (_Float16)f3.y;
            Bs[bn + 14][bk] = (_Float16)f3.z;
            Bs[bn + 15][bk] = (_Float16)f3.w;
        }
        __syncthreads();
        #pragma unroll
        for (int ks = 0; ks < 2; ++ks) {
            half8 a0 = *(half8*)&As[wm * 32 +      lr][ks * 32 + lg * 8];
            half8 a1 = *(half8*)&As[wm * 32 + 16 + lr][ks * 32 + lg * 8];
            half8 b0 = *(half8*)&Bs[wn * 32 +      lr][ks * 32 + lg * 8];
            half8 b1 = *(half8*)&Bs[wn * 32 + 16 + lr][ks * 32 + lg * 8];
            acc[0][0] = __builtin_amdgcn_mfma_f32_16x16x32_f16(a0, b0, acc[0][0], 0, 0, 0);
            acc[0][1] = __builtin_amdgcn_mfma_f32_16x16x32_f16(a0, b1, acc[0][1], 0, 0, 0);
            acc[1][0] = __builtin_amdgcn_mfma_f32_16x16x32_f16(a1, b0, acc[1][0], 0, 0, 0);
            acc[1][1] = __builtin_amdgcn_mfma_f32_16x16x32_f16(a1, b1, acc[1][1], 0, 0, 0);
        }
    }
    #pragma unroll
    for (int fm = 0; fm < 2; ++fm)
        #pragma unroll
        for (int fn = 0; fn < 2; ++fn)
            #pragma unroll
            for (int i = 0; i < 4; ++i) {
                int row = m0 + wm * 32 + fm * 16 + lg * 4 + i;
                int col = n0 + wn * 32 + fn * 16 + lr;
                float vv = acc[fm][fn][i] + bias[col];
                if (relu) vv = fmaxf(vv, 0.f);
                out[(size_t)row * N + col] = vv;
            }
}

// ---------------------------------------------------------------------------
// fp32 GEMM fallback for ragged N (classifier N=25)
__global__ __launch_bounds__(256) void gemm_kernel(const float* __restrict__ A,
                                                   const float* __restrict__ W,
                                                   const float* __restrict__ bias,
                                                   float* __restrict__ out,
                                                   int M, int K, int N, int relu) {
    __shared__ float As[16][68];
    __shared__ float Bs[16][68];
    const int tid = threadIdx.x;
    const int tx = tid & 15, ty = tid >> 4;
    const int n0 = blockIdx.x * 64;
    const int m0 = blockIdx.y * 64;
    float acc[4][4] = {};
    for (int kk = 0; kk < K; kk += 16) {
        {
            int k = tid & 15;
            int ib = tid >> 4;
            #pragma unroll
            for (int it = 0; it < 4; ++it) {
                int i = ib + it * 16;
                As[k][i] = A[(size_t)(m0 + i) * K + kk + k];
            }
        }
        {
            int j = tid & 63;
            int kb = tid >> 6;
            int n = n0 + j;
            #pragma unroll
            for (int it = 0; it < 4; ++it) {
                int k = kb + it * 4;
                Bs[k][j] = (n < N) ? W[(size_t)(kk + k) * N + n] : 0.f;
            }
        }
        __syncthreads();
        #pragma unroll
        for (int k = 0; k < 16; ++k) {
            float a[4], b[4];
            #pragma unroll
            for (int r = 0; r < 4; ++r) a[r] = As[k][ty * 4 + r];
            #pragma unroll
            for (int c = 0; c < 4; ++c) b[c] = Bs[k][tx * 4 + c];
            #pragma unroll
            for (int r = 0; r < 4; ++r)
                #pragma unroll
                for (int c = 0; c < 4; ++c)
                    acc[r][c] += a[r] * b[c];
        }
        __syncthreads();
    }
    #pragma unroll
    for (int r = 0; r < 4; ++r) {
        int m = m0 + ty * 4 + r;
        #pragma unroll
        for (int c = 0; c < 4; ++c) {
            int n = n0 + tx * 4 + c;
            if (n < N) {
                float v = acc[r][c] + bias[n];
                if (relu) v = fmaxf(v, 0.f);
                out[(size_t)m * N + n] = v;
            }
        }
    }
}

// ---------------------------------------------------------------------------
// MFMA flash attention: block = 64 q-rows x (b,h). 4 waves; wave w owns the
// 16-row i-tile [w*16, w*16+16) and ALL 64 j of each chunk -> softmax is
// wave-local. QK = 4x mfma_16x16x32_f16 (K-dim = DK = 32), rel-bias via
// MFMA in preamble, PV = 4x mfma against transposed-staged V.
struct AttnMain {
    _Float16 Ks[64][40];       // [j][d] f16, pad 40 (80B rows)
    _Float16 Vt[32][72];       // [d][j] f16, pad 72 (144B rows, 16B-aligned)
    _Float16 Ps[4][16][72];    // per-wave P tile [i][j]
};
union AttnU {
    _Float16 relH[48][40];     // rel table f16 [t][d], rows 33..47 zero
    AttnMain m;
};

__global__ __launch_bounds__(256) void attn_kernel(const float* __restrict__ q,
                                                   const float* __restrict__ k,
                                                   const float* __restrict__ v,
                                                   const float* __restrict__ rel,
                                                   const int* __restrict__ mask,
                                                   float* __restrict__ ctx) {
    __shared__ AttnU u;
    __shared__ float qrelS[64][34];
    __shared__ int   maskS[64];

    const int tid = threadIdx.x;
    const int w   = tid >> 6;
    const int l   = tid & 63;
    const int l15 = l & 15, lg = l >> 4;
    const int i0  = blockIdx.x * 64;
    const int h   = blockIdx.y;
    const int b   = blockIdx.z;
    const size_t base = ((size_t)b * SS) * DD + (size_t)h * 32;

    // --- Q fragment straight from global (row = i0 + w*16 + l15, k = lg*8..)
    half8 qfrag;
    {
        const float* qp = &q[base + (size_t)(i0 + w * 16 + l15) * DD + lg * 8];
        qfrag = cvt8(*(const float4*)qp, *(const float4*)(qp + 4));
    }

    // --- stage rel table as f16 (rows >= 33 zero)
    for (int e = tid; e < 48 * 4; e += 256) {
        int t = e >> 2, d8 = (e & 3) * 8;
        half8 hv = { (_Float16)0.f, (_Float16)0.f, (_Float16)0.f, (_Float16)0.f,
                     (_Float16)0.f, (_Float16)0.f, (_Float16)0.f, (_Float16)0.f };
        if (t < 33)
            hv = cvt8(*(const float4*)&rel[t * 32 + d8],
                      *(const float4*)&rel[t * 32 + d8 + 4]);
        *(half8*)&u.relH[t][d8] = hv;
    }
    __syncthreads();

    // --- qrel[i][t] = q_i . rel_t via 3 MFMAs per wave
    {
        floatx4 cr[3];
        #pragma unroll
        for (int jt = 0; jt < 3; ++jt) {
            half8 bfrag = *(half8*)&u.relH[jt * 16 + l15][lg * 8];
            floatx4 z = {0.f, 0.f, 0.f, 0.f};
            cr[jt] = __builtin_amdgcn_mfma_f32_16x16x32_f16(qfrag, bfrag, z, 0, 0, 0);
        }
        #pragma unroll
        for (int jt = 0; jt < 3; ++jt) {
            int col = jt * 16 + l15;
            if (col < 33) {
                #pragma unroll
                for (int ii = 0; ii < 4; ++ii)
                    qrelS[w * 16 + lg * 4 + ii][col] = cr[jt][ii];
            }
        }
    }
    __syncthreads();   // relH reads done -> union main usable

    const float scale = 0.17677669529663687f;  // 1/sqrt(32)
    floatx4 accd[2] = {{0.f, 0.f, 0.f, 0.f}, {0.f, 0.f, 0.f, 0.f}};
    float mrow[4] = {-1e30f, -1e30f, -1e30f, -1e30f};
    float lrow[4] = {0.f, 0.f, 0.f, 0.f};
    const int irow_l  = w * 16 + lg * 4;   // local row base
    const int ig_base = i0 + irow_l;       // global row base

    for (int jc = 0; jc < 8; ++jc) {
        const int j0 = jc * 64;
        __syncthreads();   // prev chunk reads of Ks/Vt done
        {   // stage K chunk [j][d] f16 (1 half8 write per thread)
            int j = tid >> 2, d8 = (tid & 3) * 8;
            const float* kp = &k[base + (size_t)(j0 + j) * DD + d8];
            *(half8*)&u.m.Ks[j][d8] = cvt8(*(const float4*)kp, *(const float4*)(kp + 4));
        }
        {   // stage V transposed [d][j] f16 (d-interleaved to spread banks)
            int j = tid >> 2, db = tid & 3;
            const float* vp = &v[base + (size_t)(j0 + j) * DD];
            #pragma unroll
            for (int s = 0; s < 8; ++s) {
                int d = db + 4 * s;
                u.m.Vt[d][j] = (_Float16)vp[d];
            }
        }
        if (tid < 64) maskS[tid] = mask[b * SS + j0 + tid];
        __syncthreads();

        // --- QK: 4 j-tiles
        floatx4 s4[4];
        #pragma unroll
        for (int jt = 0; jt < 4; ++jt) {
            half8 bfrag = *(half8*)&u.m.Ks[jt * 16 + l15][lg * 8];
            floatx4 z = {0.f, 0.f, 0.f, 0.f};
            s4[jt] = __builtin_amdgcn_mfma_f32_16x16x32_f16(qfrag, bfrag, z, 0, 0, 0);
        }
        // --- fixup (scale, rel, mask) + wave-local online softmax
        float p[4][4];
        float cmax[4] = {-1e30f, -1e30f, -1e30f, -1e30f};
        #pragma unroll
        for (int jt = 0; jt < 4; ++jt) {
            int col = jt * 16 + l15;
            int jg = j0 + col;
            int msk = maskS[col];
            #pragma unroll
            for (int ii = 0; ii < 4; ++ii) {
                int t = jg - (ig_base + ii);
                t = (t < -MAXREL ? -MAXREL : (t > MAXREL ? MAXREL : t)) + MAXREL;
                float val = s4[jt][ii] * scale + qrelS[irow_l + ii][t];
                if (msk == 0) val = -1e9f;
                p[jt][ii] = val;
                cmax[ii] = fmaxf(cmax[ii], val);
            }
        }
        #pragma unroll
        for (int wd = 1; wd < 16; wd <<= 1) {
            #pragma unroll
            for (int ii = 0; ii < 4; ++ii)
                cmax[ii] = fmaxf(cmax[ii], __shfl_xor(cmax[ii], wd));
        }
        float rs[4], csum[4] = {0.f, 0.f, 0.f, 0.f};
        #pragma unroll
        for (int ii = 0; ii < 4; ++ii) {
            float nm = fmaxf(mrow[ii], cmax[ii]);
            rs[ii] = __expf(mrow[ii] - nm);
            mrow[ii] = nm;
        }
        #pragma unroll
        for (int jt = 0; jt < 4; ++jt)
            #pragma unroll
            for (int ii = 0; ii < 4; ++ii) {
                p[jt][ii] = __expf(p[jt][ii] - mrow[ii]);
                csum[ii] += p[jt][ii];
            }
        #pragma unroll
        for (int wd = 1; wd < 16; wd <<= 1) {
            #pragma unroll
            for (int ii = 0; ii < 4; ++ii)
                csum[ii] += __shfl_xor(csum[ii], wd);
        }
        #pragma unroll
        for (int ii = 0; ii < 4; ++ii)
            lrow[ii] = lrow[ii] * rs[ii] + csum[ii];
        #pragma unroll
        for (int dt = 0; dt < 2; ++dt)
            #pragma unroll
            for (int ii = 0; ii < 4; ++ii)
                accd[dt][ii] *= rs[ii];
        // --- write P (f16) to per-wave LDS tile
        #pragma unroll
        for (int jt = 0; jt < 4; ++jt)
            #pragma unroll
            for (int ii = 0; ii < 4; ++ii)
                u.m.Ps[w][lg * 4 + ii][jt * 16 + l15] = (_Float16)p[jt][ii];
        // --- PV: acc[i][d] += P[i][j] V[j][d] (same-wave LDS dep, HW-ordered)
        #pragma unroll
        for (int kc = 0; kc < 2; ++kc) {
            half8 pa = *(half8*)&u.m.Ps[w][l15][kc * 32 + lg * 8];
            #pragma unroll
            for (int dt = 0; dt < 2; ++dt) {
                half8 vb = *(half8*)&u.m.Vt[dt * 16 + l15][kc * 32 + lg * 8];
                accd[dt] = __builtin_amdgcn_mfma_f32_16x16x32_f16(pa, vb, accd[dt], 0, 0, 0);
            }
        }
    }
    // --- epilogue: normalize + write
    #pragma unroll
    for (int ii = 0; ii < 4; ++ii) {
        float inv = 1.f / lrow[ii];
        size_t rowoff = base + (size_t)(ig_base + ii) * DD;
        #pragma unroll
        for (int dt = 0; dt < 2; ++dt)
            ctx[rowoff + dt * 16 + l15] = accd[dt][ii] * inv;
    }
}

// ---------------------------------------------------------------------------
// out[m] = LayerNorm(a[m] + res[m]) * g + beta ; one block per row, D=256
__global__ __launch_bounds__(256) void add_ln_kernel(const float* __restrict__ a,
                                                     const float* __restrict__ res,
                                                     const float* __restrict__ g,
                                                     const float* __restrict__ beta,
                                                     float* __restrict__ out) {
    __shared__ float red[4];
    int m = blockIdx.x;
    int n = threadIdx.x;
    size_t idx = (size_t)m * DD + n;
    float v = a[idx] + res[idx];
    float s = v;
    for (int w = 1; w < 64; w <<= 1) s += __shfl_xor(s, w);
    if ((n & 63) == 0) red[n >> 6] = s;
    __syncthreads();
    float mean = (red[0] + red[1] + red[2] + red[3]) * (1.f / 256.f);
    __syncthreads();
    float d = v - mean;
    float s2 = d * d;
    for (int w = 1; w < 64; w <<= 1) s2 += __shfl_xor(s2, w);
    if ((n & 63) == 0) red[n >> 6] = s2;
    __syncthreads();
    float var = (red[0] + red[1] + red[2] + red[3]) * (1.f / 256.f);
    float r = rsqrtf(var + 1e-5f);
    out[idx] = d * r * g[n] + beta[n];
}

// ---------------------------------------------------------------------------
extern "C" void kernel_launch(void* const* d_in, const int* in_sizes, int n_in,
                              void* d_out, int out_size, void* d_ws, size_t ws_size,
                              hipStream_t stream) {
    const int*   char_ids   = (const int*)d_in[0];
    const int*   bigram_ids = (const int*)d_in[1];
    const int*   mask       = (const int*)d_in[2];
    const float* char_emb   = (const float*)d_in[3];
    const float* bigram_emb = (const float*)d_in[4];
    const float* comb_W     = (const float*)d_in[5];
    const float* comb_b     = (const float*)d_in[6];
    const float* Wq         = (const float*)d_in[7];
    const float* bq         = (const float*)d_in[8];
    const float* Wk         = (const float*)d_in[9];
    const float* bk         = (const float*)d_in[10];
    const float* Wv         = (const float*)d_in[11];
    const float* bv         = (const float*)d_in[12];
    const float* Wo         = (const float*)d_in[13];
    const float* bo         = (const float*)d_in[14];
    const float* rel_emb    = (const float*)d_in[15];
    const float* ln1_g      = (const float*)d_in[16];
    const float* ln1_b      = (const float*)d_in[17];
    const float* W1         = (const float*)d_in[18];
    const float* b1         = (const float*)d_in[19];
    const float* W2         = (const float*)d_in[20];
    const float* b2         = (const float*)d_in[21];
    const float* ln2_g      = (const float*)d_in[22];
    const float* ln2_b      = (const float*)d_in[23];
    const float* cls_W      = (const float*)d_in[24];
    const float* cls_b      = (const float*)d_in[25];
    (void)in_sizes; (void)n_in; (void)out_size; (void)ws_size;

    float* ws = (float*)d_ws;
    const size_t MF = 1024 * 1024;
    float* bufA = ws;                 // 8M floats
    float* x    = ws + 8 * MF;
    float* x2   = ws + 10 * MF;
    float* qb   = ws + 12 * MF;
    float* kb   = ws + 14 * MF;
    float* vb   = ws + 16 * MF;
    float* ctxb = ws + 18 * MF;

    dim3 thr(256);

    gather_kernel<<<MM * 512 / 256, thr, 0, stream>>>(char_ids, bigram_ids,
                                                      char_emb, bigram_emb, bufA);
    mfma_gemm_kernel<<<dim3(DD / 64, MM / 64), thr, 0, stream>>>(bufA, comb_W, comb_b, x,
                                                                 MM, 2 * DD, DD, 0);
    add_pe_kernel<<<MM * DD / 256, thr, 0, stream>>>(x);

    for (int l = 0; l < LL; ++l) {
        const float* wq = Wq + (size_t)l * DD * DD;
        const float* wk = Wk + (size_t)l * DD * DD;
        const float* wv = Wv + (size_t)l * DD * DD;
        const float* wo = Wo + (size_t)l * DD * DD;
        mfma_gemm_kernel<<<dim3(DD / 64, MM / 64), thr, 0, stream>>>(x, wq, bq + l * DD, qb,
                                                                     MM, DD, DD, 0);
        mfma_gemm_kernel<<<dim3(DD / 64, MM / 64), thr, 0, stream>>>(x, wk, bk + l * DD, kb,
                                                                     MM, DD, DD, 0);
        mfma_gemm_kernel<<<dim3(DD / 64, MM / 64), thr, 0, stream>>>(x, wv, bv + l * DD, vb,
                                                                     MM, DD, DD, 0);
        attn_kernel<<<dim3(SS / 64, HH, BB), thr, 0, stream>>>(qb, kb, vb,
                                                               rel_emb + (size_t)l * 33 * 32,
                                                               mask, ctxb);
        mfma_gemm_kernel<<<dim3(DD / 64, MM / 64), thr, 0, stream>>>(ctxb, wo, bo + l * DD, qb,
                                                                     MM, DD, DD, 0);
        add_ln_kernel<<<MM, thr, 0, stream>>>(qb, x, ln1_g + l * DD, ln1_b + l * DD, x2);
        mfma_gemm_kernel<<<dim3(DFF / 64, MM / 64), thr, 0, stream>>>(x2, W1 + (size_t)l * DD * DFF,
                                                                      b1 + l * DFF, bufA,
                                                                      MM, DD, DFF, 1);
        mfma_gemm_kernel<<<dim3(DD / 64, MM / 64), thr, 0, stream>>>(bufA, W2 + (size_t)l * DFF * DD,
                                                                     b2 + l * DD, kb,
                                                                     MM, DFF, DD, 0);
        add_ln_kernel<<<MM, thr, 0, stream>>>(kb, x2, ln2_g + l * DD, ln2_b + l * DD, x);
    }
    gemm_kernel<<<dim3(1, MM / 64), thr, 0, stream>>>(x, cls_W, cls_b, (float*)d_out,
                                                      MM, DD, NLc, 0);
}